// Round 16
// baseline (238.110 us; speedup 1.0000x reference)
//
#include <hip/hip_runtime.h>

#define D_MODEL 1024
#define SEQ_L   2048
#define NHEADS  16
#define HDIM    64
#define NROWS   4096   // B*L

// Q is pre-scaled by (1/sqrt(64)) * log2(e) so softmax uses exp2 directly.
#define QSCALE 0.18033688011112042f
#define LOG2E  1.4426950408889634f

#if __has_builtin(__builtin_amdgcn_exp2f)
#define EXP2F(x) __builtin_amdgcn_exp2f(x)
#else
#define EXP2F(x) __expf((x) * 0.6931471805599453f)
#endif

typedef __attribute__((ext_vector_type(8))) short short8;
typedef __attribute__((ext_vector_type(4))) short short4v;
typedef __attribute__((ext_vector_type(4))) float floatx4;
typedef __attribute__((ext_vector_type(4))) unsigned short ushort4v;
typedef unsigned short ushort;

static __device__ __forceinline__ ushort f2bf(float f) {
    unsigned int u = __float_as_uint(f);
    u += 0x7FFFu + ((u >> 16) & 1u);
    return (ushort)(u >> 16);
}

static __device__ __forceinline__ floatx4 mfma16(short8 a, short8 b, floatx4 c) {
    return __builtin_amdgcn_mfma_f32_16x16x32_bf16(a, b, c, 0, 0, 0);
}

static __device__ __forceinline__ void store8bf(ushort* dst, float4 a, float4 b) {
    uint4 pk;
    pk.x = (unsigned)f2bf(a.x) | ((unsigned)f2bf(a.y) << 16);
    pk.y = (unsigned)f2bf(a.z) | ((unsigned)f2bf(a.w) << 16);
    pk.z = (unsigned)f2bf(b.x) | ((unsigned)f2bf(b.y) << 16);
    pk.w = (unsigned)f2bf(b.z) | ((unsigned)f2bf(b.w) << 16);
    *(uint4*)dst = pk;
}

// async global->LDS, 16B per lane.
static __device__ __forceinline__ void gll16(const ushort* g, ushort* l) {
    __builtin_amdgcn_global_load_lds(
        (const __attribute__((address_space(1))) unsigned int*)(const unsigned int*)g,
        (__attribute__((address_space(3))) unsigned int*)(unsigned int*)l,
        16, 0, 0);
}

// ---------------------------------------------------------------------------
// Kernel 0: fp32 -> bf16 conversion of x and weights.
// ---------------------------------------------------------------------------
__global__ __launch_bounds__(256) void convert_bf16(
    const float* __restrict__ x,
    const float* __restrict__ wq, const float* __restrict__ wk,
    const float* __restrict__ wv, const float* __restrict__ wo,
    ushort* __restrict__ xb, ushort* __restrict__ wb3, ushort* __restrict__ wob)
{
    const int seg = blockIdx.y;
    const float* src;
    ushort* dst;
    int n;
    if      (seg == 0) { src = x;  dst = xb;                n = 4194304; }
    else if (seg == 1) { src = wq; dst = wb3;               n = 1048576; }
    else if (seg == 2) { src = wk; dst = wb3 + 1048576;     n = 1048576; }
    else if (seg == 3) { src = wv; dst = wb3 + 2097152;     n = 1048576; }
    else               { src = wo; dst = wob;               n = 1048576; }
    const int i = (blockIdx.x * 256 + threadIdx.x) * 8;
    if (i >= n) return;
    float4 a = *(const float4*)(src + i);
    float4 b = *(const float4*)(src + i + 4);
    store8bf(dst + i, a, b);
}

// ---------------------------------------------------------------------------
// Kernel 1: fused QKV GEMM, m97 geometry: 128(M)x128(N)xBK64, grid 24x32=768,
// 4 waves as 2x2 of 64x64, acc[4][4] -> 32 MFMA + 16 ds_read_b128 per K-step
// per wave (2x the 64x128 density). K-loop LDS 32 KB.
// __launch_bounds__(256,3): 170-VGPR cap (r8's (256,4)=128 cap spilled acc ->
// 808 MB scratch traffic; r3's scattered stores had 5.4x write amp — both
// root causes fixed here: proper register budget + LDS-bounce epilogue).
// Functionally verified in r8 (passed, absmax 0.00195).
// ---------------------------------------------------------------------------
__global__ __launch_bounds__(256, 3) void gemm_qkv(
    const ushort* __restrict__ A, const ushort* __restrict__ B,
    const float* __restrict__ bq, const float* __restrict__ bk,
    const float* __restrict__ bv,
    ushort* __restrict__ Qo, ushort* __restrict__ Ko, ushort* __restrict__ Vo)
{
    __shared__ ushort Sh[16384];      // 32 KB: K-loop As+Bs, then staging
    ushort* As = Sh;                  // 128*64
    ushort* Bs = Sh + 8192;           // 128*64

    const int tid  = threadIdx.x;
    const int w    = tid >> 6;
    const int lane = tid & 63;
    const int l15  = lane & 15;
    const int quad = lane >> 4;
    const int wm   = w >> 1;          // 0..1: m half
    const int wn   = w & 1;           // 0..1: n half

    const int bm = blockIdx.y * 128;    // x-row tile
    const int bn = blockIdx.x * 128;    // weight-col tile (0..2944)
    const int z  = blockIdx.x >> 3;     // 0=Q, 1=K, 2=V

    // --- staging map: chunk ci -> row=ci>>3, slot=ci&7, global chunk g=slot^(row&7)
    const ushort* aP[4]; ushort* lA[4];
    const ushort* bP[4]; ushort* lB[4];
#pragma unroll
    for (int p = 0; p < 4; p++) {
        const int ci = tid + p * 256;
        const int r = ci >> 3, s = ci & 7;
        const int gs = (s ^ (r & 7)) * 8;
        aP[p] = A + (size_t)(bm + r) * 1024 + gs;
        lA[p] = &As[r * 64 + s * 8];
        bP[p] = B + (size_t)(bn + r) * 1024 + gs;
        lB[p] = &Bs[r * 64 + s * 8];
    }

    const int x7 = l15 & 7;

    floatx4 acc[4][4];
#pragma unroll
    for (int i = 0; i < 4; i++)
#pragma unroll
        for (int j = 0; j < 4; j++) acc[i][j] = (floatx4){0.f, 0.f, 0.f, 0.f};

    for (int k0 = 0; k0 < 1024; k0 += 64) {
        __syncthreads();
#pragma unroll
        for (int p = 0; p < 4; p++) gll16(aP[p] + k0, lA[p]);
#pragma unroll
        for (int p = 0; p < 4; p++) gll16(bP[p] + k0, lB[p]);
        __syncthreads();

#pragma unroll
        for (int kk = 0; kk < 2; kk++) {
            const int slot = ((kk * 4 + quad) ^ x7) * 8;
            short8 af[4], bf[4];
#pragma unroll
            for (int mi = 0; mi < 4; mi++)
                af[mi] = *(const short8*)&As[(wm * 64 + mi * 16 + l15) * 64 + slot];
#pragma unroll
            for (int ni = 0; ni < 4; ni++)
                bf[ni] = *(const short8*)&Bs[(wn * 64 + ni * 16 + l15) * 64 + slot];
            if (z == 2) {
#pragma unroll
                for (int mi = 0; mi < 4; mi++)
#pragma unroll
                    for (int ni = 0; ni < 4; ni++)
                        acc[mi][ni] = mfma16(af[mi], bf[ni], acc[mi][ni]);
            } else {
#pragma unroll
                for (int mi = 0; mi < 4; mi++)
#pragma unroll
                    for (int ni = 0; ni < 4; ni++)
                        acc[mi][ni] = mfma16(bf[ni], af[mi], acc[mi][ni]);
            }
        }
    }

    __syncthreads();                  // all waves done with K-loop LDS reads
    ushort* St = Sh;                  // 32 KB staging: [128 rows][128 cols]
    const int cwbase = bn & 1023;     // weight-col base within this matrix
    const int bb = bm >> 11;

    if (z == 2) {
        // ----- V: stage [hd' 0..127][li' 0..127] (rows = head-dim cols) ----
        // lane holds hd' = wn*64+ni*16+l15, li' = wm*64+mi*16+quad*4+r.
#pragma unroll
        for (int ni = 0; ni < 4; ni++) {
            const int hdp = wn * 64 + ni * 16 + l15;
            const float bvl = bv[cwbase + hdp];
            const int xr = (hdp & 7) << 2;
#pragma unroll
            for (int mi = 0; mi < 4; mi++) {
                ushort4v pk;
#pragma unroll
                for (int r = 0; r < 4; r++) pk[r] = f2bf(acc[mi][ni][r] + bvl);
                const int g = (wm * 16 + mi * 4 + quad) ^ xr;
                *(ushort4v*)&St[hdp * 128 + g * 4] = pk;
            }
        }
        __syncthreads();
        const int c = l15;            // 16 chunks of 16 B per 256-B row
#pragma unroll
        for (int t = 0; t < 8; t++) {
            const int hdp = w * 32 + t * 4 + quad;
            const int h  = (cwbase >> 6) + (hdp >> 6);
            const int hd = hdp & 63;
            const int g = (2 * c) ^ ((hdp & 7) << 2);
            uint4 vdat = *(const uint4*)&St[hdp * 128 + g * 4];
            *(uint4*)(Vo + ((size_t)(bb * NHEADS + h) * HDIM + hd) * SEQ_L
                      + (bm & 2047) + c * 8) = vdat;
        }
    } else {
        // ----- Q/K: stage [row 0..127][col 0..127] (C^T fragments) ---------
        // lane holds x-row = wm*64+mi*16+l15, cols wn*64+ni*16+quad*4+r.
        const float* bias = z ? bk : bq;
        const float scale = z ? 1.0f : QSCALE;
        ushort* outp = z ? Ko : Qo;
#pragma unroll
        for (int ni = 0; ni < 4; ni++) {
            const int colw = cwbase + wn * 64 + ni * 16 + quad * 4;
            const float4 bb4 = *(const float4*)&bias[colw];
#pragma unroll
            for (int mi = 0; mi < 4; mi++) {
                const int row = wm * 64 + mi * 16 + l15;
                ushort4v pk;
                pk[0] = f2bf((acc[mi][ni][0] + bb4.x) * scale);
                pk[1] = f2bf((acc[mi][ni][1] + bb4.y) * scale);
                pk[2] = f2bf((acc[mi][ni][2] + bb4.z) * scale);
                pk[3] = f2bf((acc[mi][ni][3] + bb4.w) * scale);
                const int g = (wn * 16 + ni * 4 + quad) ^ ((row & 7) << 2);
                *(ushort4v*)&St[row * 128 + g * 4] = pk;
            }
        }
        __syncthreads();
        const int c = l15;            // 16 chunks of 16 B per 256-B row
        const int h0 = cwbase >> 6;
        const int h  = h0 + (c >> 3);
        const int hd0 = (c & 7) * 8;
#pragma unroll
        for (int t = 0; t < 8; t++) {
            const int row = w * 32 + t * 4 + quad;
            const int li = (bm + row) & 2047;
            const int g = (2 * c) ^ ((row & 7) << 2);
            uint4 vdat = *(const uint4*)&St[row * 128 + g * 4];
            *(uint4*)(outp + ((size_t)(bb * NHEADS + h) * SEQ_L + li) * HDIM + hd0) = vdat;
        }
    }
}

// ---------------------------------------------------------------------------
// Kernel 2: flash attention, S^T formulation, FULL-K, 128-query blocks,
// 1D grid of 512 blocks with XCD-aware swizzle (r14: K/V L2-resident).
// 8 WAVES = 4 q-slots x 2 key-halves, KVBLK=128 (r15), setprio (r13).
// In-register normalize: ol[g][0] holds the full softmax denominator.
// PV uses full-rate 16x16x32 MFMA via key-slot permutation (round-2 verified).
// Structural floor ~54 us reached (r9-r15 plateau) — frozen.
// ---------------------------------------------------------------------------
__global__ __launch_bounds__(512, 4) void attn(
    const ushort* __restrict__ Q,
    const ushort* __restrict__ K,
    const ushort* __restrict__ Vt,
    const float* __restrict__ lam,
    ushort* __restrict__ Aout)
{
    __shared__ float mtab[128];
    __shared__ ushort Ks[2][128 * 64];   // 32 KB
    __shared__ ushort Vts[2][64 * 128];  // 32 KB
    __shared__ float olred[512];         //  2 KB

    const int tid  = threadIdx.x;
    const int wave = tid >> 6;           // 0..7
    const int ws   = wave & 3;           // q-slot
    const int kh   = wave >> 2;          // key half (64 of 128 keys)
    const int lane = tid & 63;
    const int l15  = lane & 15;
    const int quad = lane >> 4;

    // ---- XCD-aware swizzle: XCD c (bid%8) gets contiguous swz [64c,64c+63]
    const int bid = blockIdx.x;          // 0..511
    const int swz = (bid & 7) * 64 + (bid >> 3);
    const int qb = swz & 15;             // 0..15 (128-query tiles)
    const int h  = (swz >> 4) & 15;
    const int bz = swz >> 8;             // 0..1
    const int bh = bz * NHEADS + h;
    const int q0 = qb * 128;

    const float lambda = *lam;
    if (tid < 128) {
        float d  = (float)tid;
        float e1 = (d - 1.f) * (d - 1.f);
        float e2 = (d - 30.f) * (d - 30.f);
        mtab[tid] = LOG2E * lambda *
                    (0.8f * __expf(-2.0f * e1) + 0.4f * __expf(-0.125f * e2));
    }

    const ushort* qp =
        Q + ((size_t)bh * SEQ_L + q0 + ws * 16 + l15) * HDIM + quad * 8;
    short8 qf[2][2];
    qf[0][0] = *(const short8*)qp;
    qf[0][1] = *(const short8*)(qp + 32);
    qf[1][0] = *(const short8*)(qp + 64 * HDIM);
    qf[1][1] = *(const short8*)(qp + 64 * HDIM + 32);

    const ushort* kbase = K  + ((size_t)bh * SEQ_L) * HDIM;
    const ushort* vbase = Vt + ((size_t)bh * HDIM) * SEQ_L;

    // K staging: 1024 chunks (128 rows x 8 slots), 2/thread, dest = tid*16B
    const int kr0 = tid >> 3,          kr1 = (tid + 512) >> 3;     // 0..127
    const int ksl0 = tid & 7,          ksl1 = tid & 7;
    const ushort* kg0 = kbase + (size_t)kr0 * HDIM + (ksl0 ^ (kr0 & 7)) * 8;
    const ushort* kg1 = kbase + (size_t)kr1 * HDIM + (ksl1 ^ (kr1 & 7)) * 8;
    const int kl0 = kr0 * 64 + ksl0 * 8;
    const int kl1 = kr1 * 64 + ksl1 * 8;

    // V staging: 1024 chunks (64 rows x 16 slots), 2/thread, dest = tid*16B
    const int vr0 = tid >> 4,          vr1 = (tid + 512) >> 4;     // 0..63
    const int vsl0 = tid & 15,         vsl1 = tid & 15;
    const ushort* vg0 = vbase + (size_t)vr0 * SEQ_L + (vsl0 ^ (vr0 & 15)) * 8;
    const ushort* vg1 = vbase + (size_t)vr1 * SEQ_L + (vsl1 ^ (vr1 & 15)) * 8;
    const int vl0 = vr0 * 128 + vsl0 * 8;
    const int vl1 = vr1 * 128 + vsl1 * 8;

    floatx4 o[2][4];
#pragma unroll
    for (int g = 0; g < 2; g++)
#pragma unroll
        for (int i = 0; i < 4; i++) o[g][i] = (floatx4){0.f, 0.f, 0.f, 0.f};
    floatx4 ol[2];
    ol[0] = (floatx4){0.f, 0.f, 0.f, 0.f};
    ol[1] = (floatx4){0.f, 0.f, 0.f, 0.f};

    uint4 onesw;
    onesw.x = 0x3F803F80u; onesw.y = 0x3F803F80u;
    onesw.z = 0x3F803F80u; onesw.w = 0x3F803F80u;
    const short8 ones8 = __builtin_bit_cast(short8, onesw);

    // prologue: issue tile 0 (4 loads: 2 K chunks + 2 V chunks)
    gll16(kg0, &Ks[0][kl0]);
    gll16(kg1, &Ks[0][kl1]);
    gll16(vg0, &Vts[0][vl0]);
    gll16(vg1, &Vts[0][vl1]);

    const int xo  = l15 & 7;
    const int nt0 = kh * 4;              // this wave's 4 key sub-tiles (of 8)

    for (int t = 0; t < 16; t++) {
        const int cur = t & 1;
        __syncthreads();                 // drains tile t's loads; frees buf^1
        if (t + 1 < 16) {
            const int nb = cur ^ 1;
            const size_t ko = (size_t)(t + 1) * 128;
            gll16(kg0 + ko * HDIM, &Ks[nb][kl0]);
            gll16(kg1 + ko * HDIM, &Ks[nb][kl1]);
            gll16(vg0 + ko, &Vts[nb][vl0]);
            gll16(vg1 + ko, &Vts[nb][vl1]);
        }

        // ---- QK^T over this wave's 64 keys (4 sub-tiles) x 2 q-groups -----
        floatx4 s[2][4];
#pragma unroll
        for (int g = 0; g < 2; g++)
#pragma unroll
            for (int j = 0; j < 4; j++) s[g][j] = (floatx4){0.f, 0.f, 0.f, 0.f};
        __builtin_amdgcn_s_setprio(1);
#pragma unroll
        for (int kk = 0; kk < 2; kk++) {
            const int slot = (kk * 4 + quad) ^ xo;
#pragma unroll
            for (int j = 0; j < 4; j++) {
                const int nt = nt0 + j;
                short8 kf = *(const short8*)&Ks[cur][(nt * 16 + l15) * 64 + slot * 8];
                s[0][j] = mfma16(kf, qf[0][kk], s[0][j]);
                s[1][j] = mfma16(kf, qf[1][kk], s[1][j]);
            }
        }
        __builtin_amdgcn_s_setprio(0);

        // ---- gaussian prior mask (keys span 64-tile t64 = 2t + kh) --------
        const int t64 = 2 * t + kh;
#pragma unroll
        for (int g = 0; g < 2; g++) {
            const int tg = t64 - (qb * 2 + g);
            if (tg >= -1 && tg <= 1) {
                const int qg = q0 + g * 64 + ws * 16 + l15;
#pragma unroll
                for (int j = 0; j < 4; j++) {
                    const int kgi = t64 * 64 + j * 16 + quad * 4;
#pragma unroll
                    for (int r = 0; r < 4; r++) {
                        int dq = qg - (kgi + r);
                        int ad = dq < 0 ? -dq : dq;
                        s[g][j][r] += mtab[ad];
                    }
                }
            }
        }

        // ---- P -> bf16: 2 chunks of 32 keys per g (c=0: j0,1; c=1: j2,3) --
        short8 pb8[2][2];
#pragma unroll
        for (int g = 0; g < 2; g++) {
#pragma unroll
            for (int c = 0; c < 2; c++) {
                unsigned ur[8];
#pragma unroll
                for (int r = 0; r < 4; r++)
                    ur[r] = __float_as_uint(EXP2F(s[g][2 * c][r])) + 0x8000u;
#pragma unroll
                for (int r = 0; r < 4; r++)
                    ur[4 + r] = __float_as_uint(EXP2F(s[g][2 * c + 1][r])) + 0x8000u;
                uint4 pk;
                pk.x = __builtin_amdgcn_perm(ur[1], ur[0], 0x07060302u);
                pk.y = __builtin_amdgcn_perm(ur[3], ur[2], 0x07060302u);
                pk.z = __builtin_amdgcn_perm(ur[5], ur[4], 0x07060302u);
                pk.w = __builtin_amdgcn_perm(ur[7], ur[6], 0x07060302u);
                pb8[g][c] = __builtin_bit_cast(short8, pk);
            }
        }

        // ---- PV: key chunk cc = kh*2+c (32 keys), 16-slot V^T swizzle -----
        __builtin_amdgcn_s_setprio(1);
#pragma unroll
        for (int c = 0; c < 2; c++) {
            const int cc = kh * 2 + c;               // 0..3
            const int glo = (cc * 4 + (quad >> 1)) ^ l15;   // 4-bit slot
            const int ghi = glo ^ 2;
#pragma unroll
            for (int nt = 0; nt < 4; nt++) {
                const int rb = (nt * 16 + l15) * 128 + (quad & 1) * 4;
                short4v vlo = *(const short4v*)&Vts[cur][rb + glo * 8];
                short4v vhi = *(const short4v*)&Vts[cur][rb + ghi * 8];
                short8 vf8 = __builtin_shufflevector(vlo, vhi, 0, 1, 2, 3, 4, 5, 6, 7);
                o[0][nt] = mfma16(vf8, pb8[0][c], o[0][nt]);
                o[1][nt] = mfma16(vf8, pb8[1][c], o[1][nt]);
            }
            ol[0] = mfma16(ones8, pb8[0][c], ol[0]);
            ol[1] = mfma16(ones8, pb8[1][c], ol[1]);
        }
        __builtin_amdgcn_s_setprio(0);
    }

    // ----- cross-wave key-half reduction (Ks/Vts dead -> scratch) -----------
    __syncthreads();
    float* redb = (ws < 2) ? (float*)&Ks[0][0] : (float*)&Vts[0][0];
    const int wsl = ws & 1;              // slot within its buffer
    if (kh == 1) {
#pragma unroll
        for (int g = 0; g < 2; g++) {
#pragma unroll
            for (int nt = 0; nt < 4; nt++)
                *(floatx4*)&redb[wsl * 2048 + ((g * 4 + nt) * 64 + lane) * 4] = o[g][nt];
            olred[((ws * 2 + g) * 64) + lane] = ol[g][0];
        }
    }
    __syncthreads();
    if (kh == 0) {
#pragma unroll
        for (int g = 0; g < 2; g++) {
            const float l = ol[g][0] + olred[((ws * 2 + g) * 64) + lane];
            const float linv = 1.0f / l;
            const int qg = q0 + g * 64 + ws * 16 + l15;
            ushort* obase = Aout + ((size_t)bz * SEQ_L + qg) * D_MODEL + h * HDIM;
#pragma unroll
            for (int nt = 0; nt < 4; nt++) {
                floatx4 op = *(const floatx4*)&redb[wsl * 2048 + ((g * 4 + nt) * 64 + lane) * 4];
                ushort4v pk;
#pragma unroll
                for (int r = 0; r < 4; r++) pk[r] = f2bf((o[g][nt][r] + op[r]) * linv);
                *(ushort4v*)(obase + nt * 16 + quad * 4) = pk;
            }
        }
    }
}

// ---------------------------------------------------------------------------
// Kernel 3: output projection. 64x64xBK64 tiles, grid 16x64 = 1024 blocks,
// LDS 16 KB, SWAPPED operands -> C^T -> float4 stores.
// ---------------------------------------------------------------------------
__global__ __launch_bounds__(256, 4) void gemm_out(
    const ushort* __restrict__ A, const ushort* __restrict__ B,
    const float* __restrict__ bo, float* __restrict__ out)
{
    __shared__ ushort As[64 * 64];   // 8 KB
    __shared__ ushort Bs[64 * 64];   // 8 KB

    const int tid  = threadIdx.x;
    const int w    = tid >> 6;
    const int lane = tid & 63;
    const int l15  = lane & 15;
    const int quad = lane >> 4;

    const int bm = blockIdx.y * 64;
    const int bn = blockIdx.x * 64;

    const int ci0 = tid, ci1 = tid + 256;     // 512 chunks per tile
    const int r0 = ci0 >> 3, r1 = ci1 >> 3;
    const int s0 = ci0 & 7,  s1 = ci1 & 7;
    const ushort* aP0 = A + (size_t)(bm + r0) * 1024 + (s0 ^ (r0 & 7)) * 8;
    const ushort* aP1 = A + (size_t)(bm + r1) * 1024 + (s1 ^ (r1 & 7)) * 8;
    const ushort* bP0 = B + (size_t)(bn + r0) * 1024 + (s0 ^ (r0 & 7)) * 8;
    const ushort* bP1 = B + (size_t)(bn + r1) * 1024 + (s1 ^ (r1 & 7)) * 8;
    ushort* lA0 = &As[r0 * 64 + s0 * 8];
    ushort* lA1 = &As[r1 * 64 + s1 * 8];
    ushort* lB0 = &Bs[r0 * 64 + s0 * 8];
    ushort* lB1 = &Bs[r1 * 64 + s1 * 8];

    const int x7 = l15 & 7;

    floatx4 acc[4];
#pragma unroll
    for (int i = 0; i < 4; i++) acc[i] = (floatx4){0.f, 0.f, 0.f, 0.f};

    for (int k0 = 0; k0 < 1024; k0 += 64) {
        __syncthreads();
        gll16(aP0 + k0, lA0);
        gll16(aP1 + k0, lA1);
        gll16(bP0 + k0, lB0);
        gll16(bP1 + k0, lB1);
        __syncthreads();

#pragma unroll
        for (int kk = 0; kk < 2; kk++) {
            const int slot = ((kk * 4 + quad) ^ x7) * 8;
            short8 bf = *(const short8*)&Bs[(w * 16 + l15) * 64 + slot];
#pragma unroll
            for (int mi = 0; mi < 4; mi++) {
                short8 af = *(const short8*)&As[(mi * 16 + l15) * 64 + slot];
                acc[mi] = mfma16(bf, af, acc[mi]);
            }
        }
    }

    // D^T: lane holds x-row = l15, out-col = w*16 + quad*4 + r (consecutive)
    const int col0 = bn + w * 16 + quad * 4;
    const float4 bb4 = *(const float4*)&bo[col0];
#pragma unroll
    for (int mi = 0; mi < 4; mi++) {
        const int row = bm + mi * 16 + l15;
        float4 st;
        st.x = acc[mi][0] + bb4.x;
        st.y = acc[mi][1] + bb4.y;
        st.z = acc[mi][2] + bb4.z;
        st.w = acc[mi][3] + bb4.w;
        *(float4*)(out + (size_t)row * 1024 + col0) = st;
    }
}

// ---------------------------------------------------------------------------
extern "C" void kernel_launch(void* const* d_in, const int* in_sizes, int n_in,
                              void* d_out, int out_size, void* d_ws, size_t ws_size,
                              hipStream_t stream)
{
    const float* x   = (const float*)d_in[0];
    const float* Wq  = (const float*)d_in[1];
    const float* bq  = (const float*)d_in[2];
    const float* Wk  = (const float*)d_in[3];
    const float* bk  = (const float*)d_in[4];
    const float* Wv  = (const float*)d_in[5];
    const float* bv  = (const float*)d_in[6];
    const float* Wo  = (const float*)d_in[7];
    const float* bo  = (const float*)d_in[8];
    const float* lam = (const float*)d_in[9];
    float* out = (float*)d_out;

    const size_t NELEM = (size_t)NROWS * D_MODEL;   // 4194304
    ushort* Qw  = (ushort*)d_ws;                    //  8 MB
    ushort* Kw  = Qw + NELEM;                       //  8 MB
    ushort* Vw  = Kw + NELEM;                       //  8 MB
    ushort* XA  = Vw + NELEM;                       //  8 MB: xb, then attn out
    ushort* Wb3 = XA + NELEM;                       //  6 MB
    ushort* Wob = Wb3 + 3 * 1024 * 1024;            //  2 MB

    dim3 gc(2048, 5);
    convert_bf16<<<gc, 256, 0, stream>>>(x, Wq, Wk, Wv, Wo, XA, Wb3, Wob);

    dim3 g1(3072 / 128, NROWS / 128);  // 24 x 32 = 768 blocks
    gemm_qkv<<<g1, 256, 0, stream>>>(XA, Wb3, bq, bk, bv, Qw, Kw, Vw);

    attn<<<512, 512, 0, stream>>>(Qw, Kw, Vw, lam, XA);   // 1D, XCD-swizzled

    dim3 g3(1024 / 64, NROWS / 64);    // 16 x 64 = 1024 blocks
    gemm_out<<<g3, 256, 0, stream>>>(XA, Wob, bo, out);
}

// Round 17
// 194.004 us; speedup vs baseline: 1.2273x; 1.2273x over previous
//
#include <hip/hip_runtime.h>

#define D_MODEL 1024
#define SEQ_L   2048
#define NHEADS  16
#define HDIM    64
#define NROWS   4096   // B*L

// Q is pre-scaled by (1/sqrt(64)) * log2(e) so softmax uses exp2 directly.
#define QSCALE 0.18033688011112042f
#define LOG2E  1.4426950408889634f

#if __has_builtin(__builtin_amdgcn_exp2f)
#define EXP2F(x) __builtin_amdgcn_exp2f(x)
#else
#define EXP2F(x) __expf((x) * 0.6931471805599453f)
#endif

typedef __attribute__((ext_vector_type(8))) short short8;
typedef __attribute__((ext_vector_type(4))) short short4v;
typedef __attribute__((ext_vector_type(4))) float floatx4;
typedef __attribute__((ext_vector_type(4))) unsigned short ushort4v;
typedef unsigned short ushort;

static __device__ __forceinline__ ushort f2bf(float f) {
    unsigned int u = __float_as_uint(f);
    u += 0x7FFFu + ((u >> 16) & 1u);
    return (ushort)(u >> 16);
}

static __device__ __forceinline__ floatx4 mfma16(short8 a, short8 b, floatx4 c) {
    return __builtin_amdgcn_mfma_f32_16x16x32_bf16(a, b, c, 0, 0, 0);
}

static __device__ __forceinline__ void store8bf(ushort* dst, float4 a, float4 b) {
    uint4 pk;
    pk.x = (unsigned)f2bf(a.x) | ((unsigned)f2bf(a.y) << 16);
    pk.y = (unsigned)f2bf(a.z) | ((unsigned)f2bf(a.w) << 16);
    pk.z = (unsigned)f2bf(b.x) | ((unsigned)f2bf(b.y) << 16);
    pk.w = (unsigned)f2bf(b.z) | ((unsigned)f2bf(b.w) << 16);
    *(uint4*)dst = pk;
}

// async global->LDS, 16B per lane.
static __device__ __forceinline__ void gll16(const ushort* g, ushort* l) {
    __builtin_amdgcn_global_load_lds(
        (const __attribute__((address_space(1))) unsigned int*)(const unsigned int*)g,
        (__attribute__((address_space(3))) unsigned int*)(unsigned int*)l,
        16, 0, 0);
}

// ---------------------------------------------------------------------------
// Kernel 0: fp32 -> bf16 conversion of x and weights.
// ---------------------------------------------------------------------------
__global__ __launch_bounds__(256) void convert_bf16(
    const float* __restrict__ x,
    const float* __restrict__ wq, const float* __restrict__ wk,
    const float* __restrict__ wv, const float* __restrict__ wo,
    ushort* __restrict__ xb, ushort* __restrict__ wb3, ushort* __restrict__ wob)
{
    const int seg = blockIdx.y;
    const float* src;
    ushort* dst;
    int n;
    if      (seg == 0) { src = x;  dst = xb;                n = 4194304; }
    else if (seg == 1) { src = wq; dst = wb3;               n = 1048576; }
    else if (seg == 2) { src = wk; dst = wb3 + 1048576;     n = 1048576; }
    else if (seg == 3) { src = wv; dst = wb3 + 2097152;     n = 1048576; }
    else               { src = wo; dst = wob;               n = 1048576; }
    const int i = (blockIdx.x * 256 + threadIdx.x) * 8;
    if (i >= n) return;
    float4 a = *(const float4*)(src + i);
    float4 b = *(const float4*)(src + i + 4);
    store8bf(dst + i, a, b);
}

// ---------------------------------------------------------------------------
// Kernel 1: fused QKV GEMM. 64(M)x128(N)xBK64 tiles, 1536 blocks (1D).
// PERMANENT 64x128 (128^2 rejected 3x: r3/r8/r16 all spill or write-amp).
// NEW (T1): XCD-aware swizzle — XCD c owns weight-col chunk c (3 bx values =
// 0.75 MB of weights, L2-resident) across all 64 row tiles; same-row blocks
// within an XCD share each 128-KB A tile via L2.
// LDS-bounce epilogue: stage output tile in Bs (16 KB, free after K-loop) with
// XOR group swizzle, then read back 16B/lane and store full 128-B lines.
// ---------------------------------------------------------------------------
__global__ __launch_bounds__(256, 4) void gemm_qkv(
    const ushort* __restrict__ A, const ushort* __restrict__ B,
    const float* __restrict__ bq, const float* __restrict__ bk,
    const float* __restrict__ bv,
    ushort* __restrict__ Qo, ushort* __restrict__ Ko, ushort* __restrict__ Vo)
{
    __shared__ ushort As[64 * 64];    //  8 KB
    __shared__ ushort Bs[128 * 64];   // 16 KB (reused as epilogue staging)

    const int tid  = threadIdx.x;
    const int w    = tid >> 6;
    const int lane = tid & 63;
    const int l15  = lane & 15;
    const int quad = lane >> 4;

    // ---- T1 swizzle: bid -> (bx 0..23, by 0..63); XCD (bid&7) gets bx chunk
    const int bid = blockIdx.x;          // 0..1535
    const int xcd = bid & 7;
    const int idx = bid >> 3;            // 0..191
    const int bx  = xcd * 3 + (idx % 3); // 0..23
    const int by  = idx / 3;             // 0..63

    const int bm = by * 64;              // x-row tile
    const int bn = bx * 128;             // weight-col tile (0..3071)
    const int z  = bx >> 3;              // 0=Q, 1=K, 2=V

    // --- staging map: chunk ci -> row=ci>>3, slot=ci&7, global chunk g=slot^(row&7)
    const int ciA0 = tid,        ciA1 = tid + 256;          // As: 512 chunks
    const int rA0 = ciA0 >> 3,   rA1 = ciA1 >> 3;
    const int sA0i = ciA0 & 7,   sA1i = ciA1 & 7;
    const ushort* aP0 = A + (size_t)(bm + rA0) * 1024 + (sA0i ^ (rA0 & 7)) * 8;
    const ushort* aP1 = A + (size_t)(bm + rA1) * 1024 + (sA1i ^ (rA1 & 7)) * 8;
    ushort* lA0 = &As[rA0 * 64 + sA0i * 8];
    ushort* lA1 = &As[rA1 * 64 + sA1i * 8];

    const ushort* bP[4];
    ushort* lB[4];
#pragma unroll
    for (int p = 0; p < 4; p++) {                            // Bs: 1024 chunks
        const int ci = tid + p * 256;
        const int r = ci >> 3, s = ci & 7;
        bP[p] = B + (size_t)(bn + r) * 1024 + (s ^ (r & 7)) * 8;
        lB[p] = &Bs[r * 64 + s * 8];
    }

    const int x7 = l15 & 7;

    floatx4 acc[4][2];
#pragma unroll
    for (int i = 0; i < 4; i++)
#pragma unroll
        for (int j = 0; j < 2; j++) acc[i][j] = (floatx4){0.f, 0.f, 0.f, 0.f};

    for (int k0 = 0; k0 < 1024; k0 += 64) {
        __syncthreads();
        gll16(aP0 + k0, lA0);
        gll16(aP1 + k0, lA1);
#pragma unroll
        for (int p = 0; p < 4; p++) gll16(bP[p] + k0, lB[p]);
        __syncthreads();

#pragma unroll
        for (int kk = 0; kk < 2; kk++) {
            const int slot = ((kk * 4 + quad) ^ x7) * 8;
            short8 af[4], bf[2];
#pragma unroll
            for (int mi = 0; mi < 4; mi++)
                af[mi] = *(const short8*)&As[(mi * 16 + l15) * 64 + slot];
#pragma unroll
            for (int ni = 0; ni < 2; ni++)
                bf[ni] = *(const short8*)&Bs[(w * 32 + ni * 16 + l15) * 64 + slot];
            if (z == 2) {
#pragma unroll
                for (int mi = 0; mi < 4; mi++)
#pragma unroll
                    for (int ni = 0; ni < 2; ni++)
                        acc[mi][ni] = mfma16(af[mi], bf[ni], acc[mi][ni]);
            } else {
#pragma unroll
                for (int mi = 0; mi < 4; mi++)
#pragma unroll
                    for (int ni = 0; ni < 2; ni++)
                        acc[mi][ni] = mfma16(bf[ni], af[mi], acc[mi][ni]);
            }
        }
    }

    __syncthreads();                  // all waves done with K-loop LDS reads
    ushort* St = Bs;                  // 16 KB staging buffer
    const int cwbase = bn & 1023;     // weight-col base within this matrix
    const int bb = bm >> 11;

    if (z == 2) {
        // ----- V: stage [hd' 0..127][li' 0..63] ushort (128 B rows) --------
#pragma unroll
        for (int ni = 0; ni < 2; ni++) {
            const int hdp = w * 32 + ni * 16 + l15;
            const float bvl = bv[cwbase + hdp];
            const int xr = (hdp & 7) << 1;
#pragma unroll
            for (int mi = 0; mi < 4; mi++) {
                ushort4v pk;
#pragma unroll
                for (int r = 0; r < 4; r++) pk[r] = f2bf(acc[mi][ni][r] + bvl);
                const int gs = (mi * 4 + quad) ^ xr;
                *(ushort4v*)&St[hdp * 64 + gs * 4] = pk;
            }
        }
        __syncthreads();
        const int li0 = bm & 2047;
        const int c = lane & 7;       // 8 chunks of 16 B per 128-B row
#pragma unroll
        for (int t = 0; t < 4; t++) {
            const int hdp = w * 32 + t * 8 + (lane >> 3);
            const int h  = (cwbase >> 6) + (hdp >> 6);
            const int hd = hdp & 63;
            const int gs = (2 * c) ^ ((hdp & 7) << 1);
            uint4 vdat = *(const uint4*)&St[hdp * 64 + gs * 4];
            *(uint4*)(Vo + ((size_t)(bb * NHEADS + h) * HDIM + hd) * SEQ_L + li0 + c * 8) = vdat;
        }
    } else {
        // ----- Q/K: stage [row 0..63][col 0..127] ushort (256 B rows) ------
        const float* bias = z ? bk : bq;
        const float scale = z ? 1.0f : QSCALE;
        ushort* outp = z ? Ko : Qo;
#pragma unroll
        for (int ni = 0; ni < 2; ni++) {
            const int colw = cwbase + w * 32 + ni * 16 + quad * 4;
            const float4 bb4 = *(const float4*)&bias[colw];
#pragma unroll
            for (int mi = 0; mi < 4; mi++) {
                const int row = mi * 16 + l15;
                ushort4v pk;
                pk[0] = f2bf((acc[mi][ni][0] + bb4.x) * scale);
                pk[1] = f2bf((acc[mi][ni][1] + bb4.y) * scale);
                pk[2] = f2bf((acc[mi][ni][2] + bb4.z) * scale);
                pk[3] = f2bf((acc[mi][ni][3] + bb4.w) * scale);
                const int gs = (w * 8 + ni * 4 + quad) ^ ((row & 7) << 2);
                *(ushort4v*)&St[row * 128 + gs * 4] = pk;
            }
        }
        __syncthreads();
        const int c = l15;            // 16 chunks of 16 B per 256-B row
        const int h0 = cwbase >> 6;
        const int h  = h0 + (c >> 3);
        const int hd0 = (c & 7) * 8;
#pragma unroll
        for (int t = 0; t < 4; t++) {
            const int row = w * 16 + t * 4 + quad;
            const int li = (bm + row) & 2047;
            const int gs = (2 * c) ^ ((row & 7) << 2);
            uint4 vdat = *(const uint4*)&St[row * 128 + gs * 4];
            *(uint4*)(outp + ((size_t)(bb * NHEADS + h) * SEQ_L + li) * HDIM + hd0) = vdat;
        }
    }
}

// ---------------------------------------------------------------------------
// Kernel 2: flash attention, S^T formulation, FULL-K, 128-query blocks,
// 1D grid of 512 blocks with XCD-aware swizzle (r14: K/V L2-resident).
// 8 WAVES = 4 q-slots x 2 key-halves, KVBLK=128 (r15), setprio (r13).
// In-register normalize: ol[g][0] holds the full softmax denominator.
// PV uses full-rate 16x16x32 MFMA via key-slot permutation (round-2 verified).
// Structural floor ~54 us reached (r9-r15 plateau) — frozen.
// ---------------------------------------------------------------------------
__global__ __launch_bounds__(512, 4) void attn(
    const ushort* __restrict__ Q,
    const ushort* __restrict__ K,
    const ushort* __restrict__ Vt,
    const float* __restrict__ lam,
    ushort* __restrict__ Aout)
{
    __shared__ float mtab[128];
    __shared__ ushort Ks[2][128 * 64];   // 32 KB
    __shared__ ushort Vts[2][64 * 128];  // 32 KB
    __shared__ float olred[512];         //  2 KB

    const int tid  = threadIdx.x;
    const int wave = tid >> 6;           // 0..7
    const int ws   = wave & 3;           // q-slot
    const int kh   = wave >> 2;          // key half (64 of 128 keys)
    const int lane = tid & 63;
    const int l15  = lane & 15;
    const int quad = lane >> 4;

    // ---- XCD-aware swizzle: XCD c (bid%8) gets contiguous swz [64c,64c+63]
    const int bid = blockIdx.x;          // 0..511
    const int swz = (bid & 7) * 64 + (bid >> 3);
    const int qb = swz & 15;             // 0..15 (128-query tiles)
    const int h  = (swz >> 4) & 15;
    const int bz = swz >> 8;             // 0..1
    const int bh = bz * NHEADS + h;
    const int q0 = qb * 128;

    const float lambda = *lam;
    if (tid < 128) {
        float d  = (float)tid;
        float e1 = (d - 1.f) * (d - 1.f);
        float e2 = (d - 30.f) * (d - 30.f);
        mtab[tid] = LOG2E * lambda *
                    (0.8f * __expf(-2.0f * e1) + 0.4f * __expf(-0.125f * e2));
    }

    const ushort* qp =
        Q + ((size_t)bh * SEQ_L + q0 + ws * 16 + l15) * HDIM + quad * 8;
    short8 qf[2][2];
    qf[0][0] = *(const short8*)qp;
    qf[0][1] = *(const short8*)(qp + 32);
    qf[1][0] = *(const short8*)(qp + 64 * HDIM);
    qf[1][1] = *(const short8*)(qp + 64 * HDIM + 32);

    const ushort* kbase = K  + ((size_t)bh * SEQ_L) * HDIM;
    const ushort* vbase = Vt + ((size_t)bh * HDIM) * SEQ_L;

    // K staging: 1024 chunks (128 rows x 8 slots), 2/thread, dest = tid*16B
    const int kr0 = tid >> 3,          kr1 = (tid + 512) >> 3;     // 0..127
    const int ksl0 = tid & 7,          ksl1 = tid & 7;
    const ushort* kg0 = kbase + (size_t)kr0 * HDIM + (ksl0 ^ (kr0 & 7)) * 8;
    const ushort* kg1 = kbase + (size_t)kr1 * HDIM + (ksl1 ^ (kr1 & 7)) * 8;
    const int kl0 = kr0 * 64 + ksl0 * 8;
    const int kl1 = kr1 * 64 + ksl1 * 8;

    // V staging: 1024 chunks (64 rows x 16 slots), 2/thread, dest = tid*16B
    const int vr0 = tid >> 4,          vr1 = (tid + 512) >> 4;     // 0..63
    const int vsl0 = tid & 15,         vsl1 = tid & 15;
    const ushort* vg0 = vbase + (size_t)vr0 * SEQ_L + (vsl0 ^ (vr0 & 15)) * 8;
    const ushort* vg1 = vbase + (size_t)vr1 * SEQ_L + (vsl1 ^ (vr1 & 15)) * 8;
    const int vl0 = vr0 * 128 + vsl0 * 8;
    const int vl1 = vr1 * 128 + vsl1 * 8;

    floatx4 o[2][4];
#pragma unroll
    for (int g = 0; g < 2; g++)
#pragma unroll
        for (int i = 0; i < 4; i++) o[g][i] = (floatx4){0.f, 0.f, 0.f, 0.f};
    floatx4 ol[2];
    ol[0] = (floatx4){0.f, 0.f, 0.f, 0.f};
    ol[1] = (floatx4){0.f, 0.f, 0.f, 0.f};

    uint4 onesw;
    onesw.x = 0x3F803F80u; onesw.y = 0x3F803F80u;
    onesw.z = 0x3F803F80u; onesw.w = 0x3F803F80u;
    const short8 ones8 = __builtin_bit_cast(short8, onesw);

    // prologue: issue tile 0 (4 loads: 2 K chunks + 2 V chunks)
    gll16(kg0, &Ks[0][kl0]);
    gll16(kg1, &Ks[0][kl1]);
    gll16(vg0, &Vts[0][vl0]);
    gll16(vg1, &Vts[0][vl1]);

    const int xo  = l15 & 7;
    const int nt0 = kh * 4;              // this wave's 4 key sub-tiles (of 8)

    for (int t = 0; t < 16; t++) {
        const int cur = t & 1;
        __syncthreads();                 // drains tile t's loads; frees buf^1
        if (t + 1 < 16) {
            const int nb = cur ^ 1;
            const size_t ko = (size_t)(t + 1) * 128;
            gll16(kg0 + ko * HDIM, &Ks[nb][kl0]);
            gll16(kg1 + ko * HDIM, &Ks[nb][kl1]);
            gll16(vg0 + ko, &Vts[nb][vl0]);
            gll16(vg1 + ko, &Vts[nb][vl1]);
        }

        // ---- QK^T over this wave's 64 keys (4 sub-tiles) x 2 q-groups -----
        floatx4 s[2][4];
#pragma unroll
        for (int g = 0; g < 2; g++)
#pragma unroll
            for (int j = 0; j < 4; j++) s[g][j] = (floatx4){0.f, 0.f, 0.f, 0.f};
        __builtin_amdgcn_s_setprio(1);
#pragma unroll
        for (int kk = 0; kk < 2; kk++) {
            const int slot = (kk * 4 + quad) ^ xo;
#pragma unroll
            for (int j = 0; j < 4; j++) {
                const int nt = nt0 + j;
                short8 kf = *(const short8*)&Ks[cur][(nt * 16 + l15) * 64 + slot * 8];
                s[0][j] = mfma16(kf, qf[0][kk], s[0][j]);
                s[1][j] = mfma16(kf, qf[1][kk], s[1][j]);
            }
        }
        __builtin_amdgcn_s_setprio(0);

        // ---- gaussian prior mask (keys span 64-tile t64 = 2t + kh) --------
        const int t64 = 2 * t + kh;
#pragma unroll
        for (int g = 0; g < 2; g++) {
            const int tg = t64 - (qb * 2 + g);
            if (tg >= -1 && tg <= 1) {
                const int qg = q0 + g * 64 + ws * 16 + l15;
#pragma unroll
                for (int j = 0; j < 4; j++) {
                    const int kgi = t64 * 64 + j * 16 + quad * 4;
#pragma unroll
                    for (int r = 0; r < 4; r++) {
                        int dq = qg - (kgi + r);
                        int ad = dq < 0 ? -dq : dq;
                        s[g][j][r] += mtab[ad];
                    }
                }
            }
        }

        // ---- P -> bf16: 2 chunks of 32 keys per g (c=0: j0,1; c=1: j2,3) --
        short8 pb8[2][2];
#pragma unroll
        for (int g = 0; g < 2; g++) {
#pragma unroll
            for (int c = 0; c < 2; c++) {
                unsigned ur[8];
#pragma unroll
                for (int r = 0; r < 4; r++)
                    ur[r] = __float_as_uint(EXP2F(s[g][2 * c][r])) + 0x8000u;
#pragma unroll
                for (int r = 0; r < 4; r++)
                    ur[4 + r] = __float_as_uint(EXP2F(s[g][2 * c + 1][r])) + 0x8000u;
                uint4 pk;
                pk.x = __builtin_amdgcn_perm(ur[1], ur[0], 0x07060302u);
                pk.y = __builtin_amdgcn_perm(ur[3], ur[2], 0x07060302u);
                pk.z = __builtin_amdgcn_perm(ur[5], ur[4], 0x07060302u);
                pk.w = __builtin_amdgcn_perm(ur[7], ur[6], 0x07060302u);
                pb8[g][c] = __builtin_bit_cast(short8, pk);
            }
        }

        // ---- PV: key chunk cc = kh*2+c (32 keys), 16-slot V^T swizzle -----
        __builtin_amdgcn_s_setprio(1);
#pragma unroll
        for (int c = 0; c < 2; c++) {
            const int cc = kh * 2 + c;               // 0..3
            const int glo = (cc * 4 + (quad >> 1)) ^ l15;   // 4-bit slot
            const int ghi = glo ^ 2;
#pragma unroll
            for (int nt = 0; nt < 4; nt++) {
                const int rb = (nt * 16 + l15) * 128 + (quad & 1) * 4;
                short4v vlo = *(const short4v*)&Vts[cur][rb + glo * 8];
                short4v vhi = *(const short4v*)&Vts[cur][rb + ghi * 8];
                short8 vf8 = __builtin_shufflevector(vlo, vhi, 0, 1, 2, 3, 4, 5, 6, 7);
                o[0][nt] = mfma16(vf8, pb8[0][c], o[0][nt]);
                o[1][nt] = mfma16(vf8, pb8[1][c], o[1][nt]);
            }
            ol[0] = mfma16(ones8, pb8[0][c], ol[0]);
            ol[1] = mfma16(ones8, pb8[1][c], ol[1]);
        }
        __builtin_amdgcn_s_setprio(0);
    }

    // ----- cross-wave key-half reduction (Ks/Vts dead -> scratch) -----------
    __syncthreads();
    float* redb = (ws < 2) ? (float*)&Ks[0][0] : (float*)&Vts[0][0];
    const int wsl = ws & 1;              // slot within its buffer
    if (kh == 1) {
#pragma unroll
        for (int g = 0; g < 2; g++) {
#pragma unroll
            for (int nt = 0; nt < 4; nt++)
                *(floatx4*)&redb[wsl * 2048 + ((g * 4 + nt) * 64 + lane) * 4] = o[g][nt];
            olred[((ws * 2 + g) * 64) + lane] = ol[g][0];
        }
    }
    __syncthreads();
    if (kh == 0) {
#pragma unroll
        for (int g = 0; g < 2; g++) {
            const float l = ol[g][0] + olred[((ws * 2 + g) * 64) + lane];
            const float linv = 1.0f / l;
            const int qg = q0 + g * 64 + ws * 16 + l15;
            ushort* obase = Aout + ((size_t)bz * SEQ_L + qg) * D_MODEL + h * HDIM;
#pragma unroll
            for (int nt = 0; nt < 4; nt++) {
                floatx4 op = *(const floatx4*)&redb[wsl * 2048 + ((g * 4 + nt) * 64 + lane) * 4];
                ushort4v pk;
#pragma unroll
                for (int r = 0; r < 4; r++) pk[r] = f2bf((o[g][nt][r] + op[r]) * linv);
                *(ushort4v*)(obase + nt * 16 + quad * 4) = pk;
            }
        }
    }
}

// ---------------------------------------------------------------------------
// Kernel 3: output projection. 64x64xBK64 tiles, 1024 blocks (1D).
// NEW (T1): XCD-aware swizzle — XCD c owns out-col chunk c (2 bx values =
// 0.25 MB of Wob, L2-resident) across all 64 row tiles.
// LDS 16 KB, SWAPPED operands -> C^T -> float4 stores.
// ---------------------------------------------------------------------------
__global__ __launch_bounds__(256, 4) void gemm_out(
    const ushort* __restrict__ A, const ushort* __restrict__ B,
    const float* __restrict__ bo, float* __restrict__ out)
{
    __shared__ ushort As[64 * 64];   // 8 KB
    __shared__ ushort Bs[64 * 64];   // 8 KB

    const int tid  = threadIdx.x;
    const int w    = tid >> 6;
    const int lane = tid & 63;
    const int l15  = lane & 15;
    const int quad = lane >> 4;

    // ---- T1 swizzle: bid -> (bx 0..15, by 0..63); XCD (bid&7) gets bx chunk
    const int bid = blockIdx.x;          // 0..1023
    const int xcd = bid & 7;
    const int idx = bid >> 3;            // 0..127
    const int bx  = xcd * 2 + (idx & 1); // 0..15
    const int by  = idx >> 1;            // 0..63

    const int bm = by * 64;
    const int bn = bx * 64;

    const int ci0 = tid, ci1 = tid + 256;     // 512 chunks per tile
    const int r0 = ci0 >> 3, r1 = ci1 >> 3;
    const int s0 = ci0 & 7,  s1 = ci1 & 7;
    const ushort* aP0 = A + (size_t)(bm + r0) * 1024 + (s0 ^ (r0 & 7)) * 8;
    const ushort* aP1 = A + (size_t)(bm + r1) * 1024 + (s1 ^ (r1 & 7)) * 8;
    const ushort* bP0 = B + (size_t)(bn + r0) * 1024 + (s0 ^ (r0 & 7)) * 8;
    const ushort* bP1 = B + (size_t)(bn + r1) * 1024 + (s1 ^ (r1 & 7)) * 8;
    ushort* lA0 = &As[r0 * 64 + s0 * 8];
    ushort* lA1 = &As[r1 * 64 + s1 * 8];
    ushort* lB0 = &Bs[r0 * 64 + s0 * 8];
    ushort* lB1 = &Bs[r1 * 64 + s1 * 8];

    const int x7 = l15 & 7;

    floatx4 acc[4];
#pragma unroll
    for (int i = 0; i < 4; i++) acc[i] = (floatx4){0.f, 0.f, 0.f, 0.f};

    for (int k0 = 0; k0 < 1024; k0 += 64) {
        __syncthreads();
        gll16(aP0 + k0, lA0);
        gll16(aP1 + k0, lA1);
        gll16(bP0 + k0, lB0);
        gll16(bP1 + k0, lB1);
        __syncthreads();

#pragma unroll
        for (int kk = 0; kk < 2; kk++) {
            const int slot = ((kk * 4 + quad) ^ x7) * 8;
            short8 bf = *(const short8*)&Bs[(w * 16 + l15) * 64 + slot];
#pragma unroll
            for (int mi = 0; mi < 4; mi++) {
                short8 af = *(const short8*)&As[(mi * 16 + l15) * 64 + slot];
                acc[mi] = mfma16(bf, af, acc[mi]);
            }
        }
    }

    // D^T: lane holds x-row = l15, out-col = w*16 + quad*4 + r (consecutive)
    const int col0 = bn + w * 16 + quad * 4;
    const float4 bb4 = *(const float4*)&bo[col0];
#pragma unroll
    for (int mi = 0; mi < 4; mi++) {
        const int row = bm + mi * 16 + l15;
        float4 st;
        st.x = acc[mi][0] + bb4.x;
        st.y = acc[mi][1] + bb4.y;
        st.z = acc[mi][2] + bb4.z;
        st.w = acc[mi][3] + bb4.w;
        *(float4*)(out + (size_t)row * 1024 + col0) = st;
    }
}

// ---------------------------------------------------------------------------
extern "C" void kernel_launch(void* const* d_in, const int* in_sizes, int n_in,
                              void* d_out, int out_size, void* d_ws, size_t ws_size,
                              hipStream_t stream)
{
    const float* x   = (const float*)d_in[0];
    const float* Wq  = (const float*)d_in[1];
    const float* bq  = (const float*)d_in[2];
    const float* Wk  = (const float*)d_in[3];
    const float* bk  = (const float*)d_in[4];
    const float* Wv  = (const float*)d_in[5];
    const float* bv  = (const float*)d_in[6];
    const float* Wo  = (const float*)d_in[7];
    const float* bo  = (const float*)d_in[8];
    const float* lam = (const float*)d_in[9];
    float* out = (float*)d_out;

    const size_t NELEM = (size_t)NROWS * D_MODEL;   // 4194304
    ushort* Qw  = (ushort*)d_ws;                    //  8 MB
    ushort* Kw  = Qw + NELEM;                       //  8 MB
    ushort* Vw  = Kw + NELEM;                       //  8 MB
    ushort* XA  = Vw + NELEM;                       //  8 MB: xb, then attn out
    ushort* Wb3 = XA + NELEM;                       //  6 MB
    ushort* Wob = Wb3 + 3 * 1024 * 1024;            //  2 MB

    dim3 gc(2048, 5);
    convert_bf16<<<gc, 256, 0, stream>>>(x, Wq, Wk, Wv, Wo, XA, Wb3, Wob);

    gemm_qkv<<<1536, 256, 0, stream>>>(XA, Wb3, bq, bk, bv, Qw, Kw, Vw);

    attn<<<512, 512, 0, stream>>>(Qw, Kw, Vw, lam, XA);   // 1D, XCD-swizzled

    gemm_out<<<1024, 256, 0, stream>>>(XA, Wob, bo, out); // 1D, XCD-swizzled
}

// Round 18
// 187.199 us; speedup vs baseline: 1.2720x; 1.0363x over previous
//
#include <hip/hip_runtime.h>

#define D_MODEL 1024
#define SEQ_L   2048
#define NHEADS  16
#define HDIM    64
#define NROWS   4096   // B*L

// Q is pre-scaled by (1/sqrt(64)) * log2(e) so softmax uses exp2 directly.
#define QSCALE 0.18033688011112042f
#define LOG2E  1.4426950408889634f

#if __has_builtin(__builtin_amdgcn_exp2f)
#define EXP2F(x) __builtin_amdgcn_exp2f(x)
#else
#define EXP2F(x) __expf((x) * 0.6931471805599453f)
#endif

typedef __attribute__((ext_vector_type(8))) short short8;
typedef __attribute__((ext_vector_type(4))) short short4v;
typedef __attribute__((ext_vector_type(4))) float floatx4;
typedef __attribute__((ext_vector_type(4))) unsigned short ushort4v;
typedef unsigned short ushort;

static __device__ __forceinline__ ushort f2bf(float f) {
    unsigned int u = __float_as_uint(f);
    u += 0x7FFFu + ((u >> 16) & 1u);
    return (ushort)(u >> 16);
}

static __device__ __forceinline__ floatx4 mfma16(short8 a, short8 b, floatx4 c) {
    return __builtin_amdgcn_mfma_f32_16x16x32_bf16(a, b, c, 0, 0, 0);
}

static __device__ __forceinline__ void store8bf(ushort* dst, float4 a, float4 b) {
    uint4 pk;
    pk.x = (unsigned)f2bf(a.x) | ((unsigned)f2bf(a.y) << 16);
    pk.y = (unsigned)f2bf(a.z) | ((unsigned)f2bf(a.w) << 16);
    pk.z = (unsigned)f2bf(b.x) | ((unsigned)f2bf(b.y) << 16);
    pk.w = (unsigned)f2bf(b.z) | ((unsigned)f2bf(b.w) << 16);
    *(uint4*)dst = pk;
}

// async global->LDS, 16B per lane.
static __device__ __forceinline__ void gll16(const ushort* g, ushort* l) {
    __builtin_amdgcn_global_load_lds(
        (const __attribute__((address_space(1))) unsigned int*)(const unsigned int*)g,
        (__attribute__((address_space(3))) unsigned int*)(unsigned int*)l,
        16, 0, 0);
}

// ---------------------------------------------------------------------------
// Kernel 0: fp32 -> bf16 conversion of x and weights.
// ---------------------------------------------------------------------------
__global__ __launch_bounds__(256) void convert_bf16(
    const float* __restrict__ x,
    const float* __restrict__ wq, const float* __restrict__ wk,
    const float* __restrict__ wv, const float* __restrict__ wo,
    ushort* __restrict__ xb, ushort* __restrict__ wb3, ushort* __restrict__ wob)
{
    const int seg = blockIdx.y;
    const float* src;
    ushort* dst;
    int n;
    if      (seg == 0) { src = x;  dst = xb;                n = 4194304; }
    else if (seg == 1) { src = wq; dst = wb3;               n = 1048576; }
    else if (seg == 2) { src = wk; dst = wb3 + 1048576;     n = 1048576; }
    else if (seg == 3) { src = wv; dst = wb3 + 2097152;     n = 1048576; }
    else               { src = wo; dst = wob;               n = 1048576; }
    const int i = (blockIdx.x * 256 + threadIdx.x) * 8;
    if (i >= n) return;
    float4 a = *(const float4*)(src + i);
    float4 b = *(const float4*)(src + i + 4);
    store8bf(dst + i, a, b);
}

// ---------------------------------------------------------------------------
// Kernel 1: fused QKV GEMM. 64(M)x128(N)xBK64 tiles, grid 24x64 = 1536 blocks.
// PERMANENT 64x128 (128^2 rejected 3x: r3/r8/r16 — write-amp or VGPR spill).
// T1 swizzle on this kernel tested r17: neutral (not locality-bound) — 2D grid.
// LDS-bounce epilogue: stage output tile in Bs (16 KB, free after K-loop) with
// XOR group swizzle, then read back 16B/lane and store full 128-B lines.
// ---------------------------------------------------------------------------
__global__ __launch_bounds__(256, 4) void gemm_qkv(
    const ushort* __restrict__ A, const ushort* __restrict__ B,
    const float* __restrict__ bq, const float* __restrict__ bk,
    const float* __restrict__ bv,
    ushort* __restrict__ Qo, ushort* __restrict__ Ko, ushort* __restrict__ Vo)
{
    __shared__ ushort As[64 * 64];    //  8 KB
    __shared__ ushort Bs[128 * 64];   // 16 KB (reused as epilogue staging)

    const int tid  = threadIdx.x;
    const int w    = tid >> 6;
    const int lane = tid & 63;
    const int l15  = lane & 15;
    const int quad = lane >> 4;

    const int bm = blockIdx.y * 64;     // x-row tile
    const int bn = blockIdx.x * 128;    // weight-col tile (0..3071)
    const int z  = blockIdx.x >> 3;     // 0=Q, 1=K, 2=V

    // --- staging map: chunk ci -> row=ci>>3, slot=ci&7, global chunk g=slot^(row&7)
    const int ciA0 = tid,        ciA1 = tid + 256;          // As: 512 chunks
    const int rA0 = ciA0 >> 3,   rA1 = ciA1 >> 3;
    const int sA0i = ciA0 & 7,   sA1i = ciA1 & 7;
    const ushort* aP0 = A + (size_t)(bm + rA0) * 1024 + (sA0i ^ (rA0 & 7)) * 8;
    const ushort* aP1 = A + (size_t)(bm + rA1) * 1024 + (sA1i ^ (rA1 & 7)) * 8;
    ushort* lA0 = &As[rA0 * 64 + sA0i * 8];
    ushort* lA1 = &As[rA1 * 64 + sA1i * 8];

    const ushort* bP[4];
    ushort* lB[4];
#pragma unroll
    for (int p = 0; p < 4; p++) {                            // Bs: 1024 chunks
        const int ci = tid + p * 256;
        const int r = ci >> 3, s = ci & 7;
        bP[p] = B + (size_t)(bn + r) * 1024 + (s ^ (r & 7)) * 8;
        lB[p] = &Bs[r * 64 + s * 8];
    }

    const int x7 = l15 & 7;

    floatx4 acc[4][2];
#pragma unroll
    for (int i = 0; i < 4; i++)
#pragma unroll
        for (int j = 0; j < 2; j++) acc[i][j] = (floatx4){0.f, 0.f, 0.f, 0.f};

    for (int k0 = 0; k0 < 1024; k0 += 64) {
        __syncthreads();
        gll16(aP0 + k0, lA0);
        gll16(aP1 + k0, lA1);
#pragma unroll
        for (int p = 0; p < 4; p++) gll16(bP[p] + k0, lB[p]);
        __syncthreads();

#pragma unroll
        for (int kk = 0; kk < 2; kk++) {
            const int slot = ((kk * 4 + quad) ^ x7) * 8;
            short8 af[4], bf[2];
#pragma unroll
            for (int mi = 0; mi < 4; mi++)
                af[mi] = *(const short8*)&As[(mi * 16 + l15) * 64 + slot];
#pragma unroll
            for (int ni = 0; ni < 2; ni++)
                bf[ni] = *(const short8*)&Bs[(w * 32 + ni * 16 + l15) * 64 + slot];
            if (z == 2) {
#pragma unroll
                for (int mi = 0; mi < 4; mi++)
#pragma unroll
                    for (int ni = 0; ni < 2; ni++)
                        acc[mi][ni] = mfma16(af[mi], bf[ni], acc[mi][ni]);
            } else {
#pragma unroll
                for (int mi = 0; mi < 4; mi++)
#pragma unroll
                    for (int ni = 0; ni < 2; ni++)
                        acc[mi][ni] = mfma16(bf[ni], af[mi], acc[mi][ni]);
            }
        }
    }

    __syncthreads();                  // all waves done with K-loop LDS reads
    ushort* St = Bs;                  // 16 KB staging buffer
    const int cwbase = bn & 1023;     // weight-col base within this matrix
    const int bb = bm >> 11;

    if (z == 2) {
        // ----- V: stage [hd' 0..127][li' 0..63] ushort (128 B rows) --------
#pragma unroll
        for (int ni = 0; ni < 2; ni++) {
            const int hdp = w * 32 + ni * 16 + l15;
            const float bvl = bv[cwbase + hdp];
            const int xr = (hdp & 7) << 1;
#pragma unroll
            for (int mi = 0; mi < 4; mi++) {
                ushort4v pk;
#pragma unroll
                for (int r = 0; r < 4; r++) pk[r] = f2bf(acc[mi][ni][r] + bvl);
                const int gs = (mi * 4 + quad) ^ xr;
                *(ushort4v*)&St[hdp * 64 + gs * 4] = pk;
            }
        }
        __syncthreads();
        const int li0 = bm & 2047;
        const int c = lane & 7;       // 8 chunks of 16 B per 128-B row
#pragma unroll
        for (int t = 0; t < 4; t++) {
            const int hdp = w * 32 + t * 8 + (lane >> 3);
            const int h  = (cwbase >> 6) + (hdp >> 6);
            const int hd = hdp & 63;
            const int gs = (2 * c) ^ ((hdp & 7) << 1);
            uint4 vdat = *(const uint4*)&St[hdp * 64 + gs * 4];
            *(uint4*)(Vo + ((size_t)(bb * NHEADS + h) * HDIM + hd) * SEQ_L + li0 + c * 8) = vdat;
        }
    } else {
        // ----- Q/K: stage [row 0..63][col 0..127] ushort (256 B rows) ------
        const float* bias = z ? bk : bq;
        const float scale = z ? 1.0f : QSCALE;
        ushort* outp = z ? Ko : Qo;
#pragma unroll
        for (int ni = 0; ni < 2; ni++) {
            const int colw = cwbase + w * 32 + ni * 16 + quad * 4;
            const float4 bb4 = *(const float4*)&bias[colw];
#pragma unroll
            for (int mi = 0; mi < 4; mi++) {
                const int row = mi * 16 + l15;
                ushort4v pk;
                pk[0] = f2bf((acc[mi][ni][0] + bb4.x) * scale);
                pk[1] = f2bf((acc[mi][ni][1] + bb4.y) * scale);
                pk[2] = f2bf((acc[mi][ni][2] + bb4.z) * scale);
                pk[3] = f2bf((acc[mi][ni][3] + bb4.w) * scale);
                const int gs = (w * 8 + ni * 4 + quad) ^ ((row & 7) << 2);
                *(ushort4v*)&St[row * 128 + gs * 4] = pk;
            }
        }
        __syncthreads();
        const int c = l15;            // 16 chunks of 16 B per 256-B row
        const int h0 = cwbase >> 6;
        const int h  = h0 + (c >> 3);
        const int hd0 = (c & 7) * 8;
#pragma unroll
        for (int t = 0; t < 4; t++) {
            const int row = w * 16 + t * 4 + quad;
            const int li = (bm + row) & 2047;
            const int gs = (2 * c) ^ ((row & 7) << 2);
            uint4 vdat = *(const uint4*)&St[row * 128 + gs * 4];
            *(uint4*)(outp + ((size_t)(bb * NHEADS + h) * SEQ_L + li) * HDIM + hd0) = vdat;
        }
    }
}

// ---------------------------------------------------------------------------
// Kernel 2: flash attention, S^T formulation, FULL-K, 128-query blocks,
// 1D grid of 512 blocks with XCD-aware swizzle (r14: K/V L2-resident,
// FETCH 69.7->12.3 MB). 8 WAVES = 4 q-slots x 2 key-halves (r9),
// KVBLK=128 (r15), setprio around MFMA clusters (r13).
// In-register normalize: ol[g][0] holds the full softmax denominator.
// PV uses full-rate 16x16x32 MFMA via key-slot permutation (round-2 verified).
// Structural floor ~54 us (r9-r15 plateau: MfmaUtil 28 / VALU 46 / HBM 6,
// latency-bound; counted-vmcnt, KVBLK, q-split, VALU-cuts all neutral).
// ---------------------------------------------------------------------------
__global__ __launch_bounds__(512, 4) void attn(
    const ushort* __restrict__ Q,
    const ushort* __restrict__ K,
    const ushort* __restrict__ Vt,
    const float* __restrict__ lam,
    ushort* __restrict__ Aout)
{
    __shared__ float mtab[128];
    __shared__ ushort Ks[2][128 * 64];   // 32 KB
    __shared__ ushort Vts[2][64 * 128];  // 32 KB
    __shared__ float olred[512];         //  2 KB

    const int tid  = threadIdx.x;
    const int wave = tid >> 6;           // 0..7
    const int ws   = wave & 3;           // q-slot
    const int kh   = wave >> 2;          // key half (64 of 128 keys)
    const int lane = tid & 63;
    const int l15  = lane & 15;
    const int quad = lane >> 4;

    // ---- XCD-aware swizzle: XCD c (bid%8) gets contiguous swz [64c,64c+63]
    const int bid = blockIdx.x;          // 0..511
    const int swz = (bid & 7) * 64 + (bid >> 3);
    const int qb = swz & 15;             // 0..15 (128-query tiles)
    const int h  = (swz >> 4) & 15;
    const int bz = swz >> 8;             // 0..1
    const int bh = bz * NHEADS + h;
    const int q0 = qb * 128;

    const float lambda = *lam;
    if (tid < 128) {
        float d  = (float)tid;
        float e1 = (d - 1.f) * (d - 1.f);
        float e2 = (d - 30.f) * (d - 30.f);
        mtab[tid] = LOG2E * lambda *
                    (0.8f * __expf(-2.0f * e1) + 0.4f * __expf(-0.125f * e2));
    }

    const ushort* qp =
        Q + ((size_t)bh * SEQ_L + q0 + ws * 16 + l15) * HDIM + quad * 8;
    short8 qf[2][2];
    qf[0][0] = *(const short8*)qp;
    qf[0][1] = *(const short8*)(qp + 32);
    qf[1][0] = *(const short8*)(qp + 64 * HDIM);
    qf[1][1] = *(const short8*)(qp + 64 * HDIM + 32);

    const ushort* kbase = K  + ((size_t)bh * SEQ_L) * HDIM;
    const ushort* vbase = Vt + ((size_t)bh * HDIM) * SEQ_L;

    // K staging: 1024 chunks (128 rows x 8 slots), 2/thread, dest = tid*16B
    const int kr0 = tid >> 3,          kr1 = (tid + 512) >> 3;     // 0..127
    const int ksl0 = tid & 7,          ksl1 = tid & 7;
    const ushort* kg0 = kbase + (size_t)kr0 * HDIM + (ksl0 ^ (kr0 & 7)) * 8;
    const ushort* kg1 = kbase + (size_t)kr1 * HDIM + (ksl1 ^ (kr1 & 7)) * 8;
    const int kl0 = kr0 * 64 + ksl0 * 8;
    const int kl1 = kr1 * 64 + ksl1 * 8;

    // V staging: 1024 chunks (64 rows x 16 slots), 2/thread, dest = tid*16B
    const int vr0 = tid >> 4,          vr1 = (tid + 512) >> 4;     // 0..63
    const int vsl0 = tid & 15,         vsl1 = tid & 15;
    const ushort* vg0 = vbase + (size_t)vr0 * SEQ_L + (vsl0 ^ (vr0 & 15)) * 8;
    const ushort* vg1 = vbase + (size_t)vr1 * SEQ_L + (vsl1 ^ (vr1 & 15)) * 8;
    const int vl0 = vr0 * 128 + vsl0 * 8;
    const int vl1 = vr1 * 128 + vsl1 * 8;

    floatx4 o[2][4];
#pragma unroll
    for (int g = 0; g < 2; g++)
#pragma unroll
        for (int i = 0; i < 4; i++) o[g][i] = (floatx4){0.f, 0.f, 0.f, 0.f};
    floatx4 ol[2];
    ol[0] = (floatx4){0.f, 0.f, 0.f, 0.f};
    ol[1] = (floatx4){0.f, 0.f, 0.f, 0.f};

    uint4 onesw;
    onesw.x = 0x3F803F80u; onesw.y = 0x3F803F80u;
    onesw.z = 0x3F803F80u; onesw.w = 0x3F803F80u;
    const short8 ones8 = __builtin_bit_cast(short8, onesw);

    // prologue: issue tile 0 (4 loads: 2 K chunks + 2 V chunks)
    gll16(kg0, &Ks[0][kl0]);
    gll16(kg1, &Ks[0][kl1]);
    gll16(vg0, &Vts[0][vl0]);
    gll16(vg1, &Vts[0][vl1]);

    const int xo  = l15 & 7;
    const int nt0 = kh * 4;              // this wave's 4 key sub-tiles (of 8)

    for (int t = 0; t < 16; t++) {
        const int cur = t & 1;
        __syncthreads();                 // drains tile t's loads; frees buf^1
        if (t + 1 < 16) {
            const int nb = cur ^ 1;
            const size_t ko = (size_t)(t + 1) * 128;
            gll16(kg0 + ko * HDIM, &Ks[nb][kl0]);
            gll16(kg1 + ko * HDIM, &Ks[nb][kl1]);
            gll16(vg0 + ko, &Vts[nb][vl0]);
            gll16(vg1 + ko, &Vts[nb][vl1]);
        }

        // ---- QK^T over this wave's 64 keys (4 sub-tiles) x 2 q-groups -----
        floatx4 s[2][4];
#pragma unroll
        for (int g = 0; g < 2; g++)
#pragma unroll
            for (int j = 0; j < 4; j++) s[g][j] = (floatx4){0.f, 0.f, 0.f, 0.f};
        __builtin_amdgcn_s_setprio(1);
#pragma unroll
        for (int kk = 0; kk < 2; kk++) {
            const int slot = (kk * 4 + quad) ^ xo;
#pragma unroll
            for (int j = 0; j < 4; j++) {
                const int nt = nt0 + j;
                short8 kf = *(const short8*)&Ks[cur][(nt * 16 + l15) * 64 + slot * 8];
                s[0][j] = mfma16(kf, qf[0][kk], s[0][j]);
                s[1][j] = mfma16(kf, qf[1][kk], s[1][j]);
            }
        }
        __builtin_amdgcn_s_setprio(0);

        // ---- gaussian prior mask (keys span 64-tile t64 = 2t + kh) --------
        const int t64 = 2 * t + kh;
#pragma unroll
        for (int g = 0; g < 2; g++) {
            const int tg = t64 - (qb * 2 + g);
            if (tg >= -1 && tg <= 1) {
                const int qg = q0 + g * 64 + ws * 16 + l15;
#pragma unroll
                for (int j = 0; j < 4; j++) {
                    const int kgi = t64 * 64 + j * 16 + quad * 4;
#pragma unroll
                    for (int r = 0; r < 4; r++) {
                        int dq = qg - (kgi + r);
                        int ad = dq < 0 ? -dq : dq;
                        s[g][j][r] += mtab[ad];
                    }
                }
            }
        }

        // ---- P -> bf16: 2 chunks of 32 keys per g (c=0: j0,1; c=1: j2,3) --
        short8 pb8[2][2];
#pragma unroll
        for (int g = 0; g < 2; g++) {
#pragma unroll
            for (int c = 0; c < 2; c++) {
                unsigned ur[8];
#pragma unroll
                for (int r = 0; r < 4; r++)
                    ur[r] = __float_as_uint(EXP2F(s[g][2 * c][r])) + 0x8000u;
#pragma unroll
                for (int r = 0; r < 4; r++)
                    ur[4 + r] = __float_as_uint(EXP2F(s[g][2 * c + 1][r])) + 0x8000u;
                uint4 pk;
                pk.x = __builtin_amdgcn_perm(ur[1], ur[0], 0x07060302u);
                pk.y = __builtin_amdgcn_perm(ur[3], ur[2], 0x07060302u);
                pk.z = __builtin_amdgcn_perm(ur[5], ur[4], 0x07060302u);
                pk.w = __builtin_amdgcn_perm(ur[7], ur[6], 0x07060302u);
                pb8[g][c] = __builtin_bit_cast(short8, pk);
            }
        }

        // ---- PV: key chunk cc = kh*2+c (32 keys), 16-slot V^T swizzle -----
        __builtin_amdgcn_s_setprio(1);
#pragma unroll
        for (int c = 0; c < 2; c++) {
            const int cc = kh * 2 + c;               // 0..3
            const int glo = (cc * 4 + (quad >> 1)) ^ l15;   // 4-bit slot
            const int ghi = glo ^ 2;
#pragma unroll
            for (int nt = 0; nt < 4; nt++) {
                const int rb = (nt * 16 + l15) * 128 + (quad & 1) * 4;
                short4v vlo = *(const short4v*)&Vts[cur][rb + glo * 8];
                short4v vhi = *(const short4v*)&Vts[cur][rb + ghi * 8];
                short8 vf8 = __builtin_shufflevector(vlo, vhi, 0, 1, 2, 3, 4, 5, 6, 7);
                o[0][nt] = mfma16(vf8, pb8[0][c], o[0][nt]);
                o[1][nt] = mfma16(vf8, pb8[1][c], o[1][nt]);
            }
            ol[0] = mfma16(ones8, pb8[0][c], ol[0]);
            ol[1] = mfma16(ones8, pb8[1][c], ol[1]);
        }
        __builtin_amdgcn_s_setprio(0);
    }

    // ----- cross-wave key-half reduction (Ks/Vts dead -> scratch) -----------
    __syncthreads();
    float* redb = (ws < 2) ? (float*)&Ks[0][0] : (float*)&Vts[0][0];
    const int wsl = ws & 1;              // slot within its buffer
    if (kh == 1) {
#pragma unroll
        for (int g = 0; g < 2; g++) {
#pragma unroll
            for (int nt = 0; nt < 4; nt++)
                *(floatx4*)&redb[wsl * 2048 + ((g * 4 + nt) * 64 + lane) * 4] = o[g][nt];
            olred[((ws * 2 + g) * 64) + lane] = ol[g][0];
        }
    }
    __syncthreads();
    if (kh == 0) {
#pragma unroll
        for (int g = 0; g < 2; g++) {
            const float l = ol[g][0] + olred[((ws * 2 + g) * 64) + lane];
            const float linv = 1.0f / l;
            const int qg = q0 + g * 64 + ws * 16 + l15;
            ushort* obase = Aout + ((size_t)bz * SEQ_L + qg) * D_MODEL + h * HDIM;
#pragma unroll
            for (int nt = 0; nt < 4; nt++) {
                floatx4 op = *(const floatx4*)&redb[wsl * 2048 + ((g * 4 + nt) * 64 + lane) * 4];
                ushort4v pk;
#pragma unroll
                for (int r = 0; r < 4; r++) pk[r] = f2bf((o[g][nt][r] + op[r]) * linv);
                *(ushort4v*)(obase + nt * 16 + quad * 4) = pk;
            }
        }
    }
}

// ---------------------------------------------------------------------------
// Kernel 3: output projection. 64x64xBK64 tiles, grid 16x64 = 1024 blocks,
// LDS 16 KB, SWAPPED operands -> C^T -> float4 stores. (T1 tested r17: neutral.)
// ---------------------------------------------------------------------------
__global__ __launch_bounds__(256, 4) void gemm_out(
    const ushort* __restrict__ A, const ushort* __restrict__ B,
    const float* __restrict__ bo, float* __restrict__ out)
{
    __shared__ ushort As[64 * 64];   // 8 KB
    __shared__ ushort Bs[64 * 64];   // 8 KB

    const int tid  = threadIdx.x;
    const int w    = tid >> 6;
    const int lane = tid & 63;
    const int l15  = lane & 15;
    const int quad = lane >> 4;

    const int bm = blockIdx.y * 64;
    const int bn = blockIdx.x * 64;

    const int ci0 = tid, ci1 = tid + 256;     // 512 chunks per tile
    const int r0 = ci0 >> 3, r1 = ci1 >> 3;
    const int s0 = ci0 & 7,  s1 = ci1 & 7;
    const ushort* aP0 = A + (size_t)(bm + r0) * 1024 + (s0 ^ (r0 & 7)) * 8;
    const ushort* aP1 = A + (size_t)(bm + r1) * 1024 + (s1 ^ (r1 & 7)) * 8;
    const ushort* bP0 = B + (size_t)(bn + r0) * 1024 + (s0 ^ (r0 & 7)) * 8;
    const ushort* bP1 = B + (size_t)(bn + r1) * 1024 + (s1 ^ (r1 & 7)) * 8;
    ushort* lA0 = &As[r0 * 64 + s0 * 8];
    ushort* lA1 = &As[r1 * 64 + s1 * 8];
    ushort* lB0 = &Bs[r0 * 64 + s0 * 8];
    ushort* lB1 = &Bs[r1 * 64 + s1 * 8];

    const int x7 = l15 & 7;

    floatx4 acc[4];
#pragma unroll
    for (int i = 0; i < 4; i++) acc[i] = (floatx4){0.f, 0.f, 0.f, 0.f};

    for (int k0 = 0; k0 < 1024; k0 += 64) {
        __syncthreads();
        gll16(aP0 + k0, lA0);
        gll16(aP1 + k0, lA1);
        gll16(bP0 + k0, lB0);
        gll16(bP1 + k0, lB1);
        __syncthreads();

#pragma unroll
        for (int kk = 0; kk < 2; kk++) {
            const int slot = ((kk * 4 + quad) ^ x7) * 8;
            short8 bf = *(const short8*)&Bs[(w * 16 + l15) * 64 + slot];
#pragma unroll
            for (int mi = 0; mi < 4; mi++) {
                short8 af = *(const short8*)&As[(mi * 16 + l15) * 64 + slot];
                acc[mi] = mfma16(bf, af, acc[mi]);
            }
        }
    }

    // D^T: lane holds x-row = l15, out-col = w*16 + quad*4 + r (consecutive)
    const int col0 = bn + w * 16 + quad * 4;
    const float4 bb4 = *(const float4*)&bo[col0];
#pragma unroll
    for (int mi = 0; mi < 4; mi++) {
        const int row = bm + mi * 16 + l15;
        float4 st;
        st.x = acc[mi][0] + bb4.x;
        st.y = acc[mi][1] + bb4.y;
        st.z = acc[mi][2] + bb4.z;
        st.w = acc[mi][3] + bb4.w;
        *(float4*)(out + (size_t)row * 1024 + col0) = st;
    }
}

// ---------------------------------------------------------------------------
extern "C" void kernel_launch(void* const* d_in, const int* in_sizes, int n_in,
                              void* d_out, int out_size, void* d_ws, size_t ws_size,
                              hipStream_t stream)
{
    const float* x   = (const float*)d_in[0];
    const float* Wq  = (const float*)d_in[1];
    const float* bq  = (const float*)d_in[2];
    const float* Wk  = (const float*)d_in[3];
    const float* bk  = (const float*)d_in[4];
    const float* Wv  = (const float*)d_in[5];
    const float* bv  = (const float*)d_in[6];
    const float* Wo  = (const float*)d_in[7];
    const float* bo  = (const float*)d_in[8];
    const float* lam = (const float*)d_in[9];
    float* out = (float*)d_out;

    const size_t NELEM = (size_t)NROWS * D_MODEL;   // 4194304
    ushort* Qw  = (ushort*)d_ws;                    //  8 MB
    ushort* Kw  = Qw + NELEM;                       //  8 MB
    ushort* Vw  = Kw + NELEM;                       //  8 MB
    ushort* XA  = Vw + NELEM;                       //  8 MB: xb, then attn out
    ushort* Wb3 = XA + NELEM;                       //  6 MB
    ushort* Wob = Wb3 + 3 * 1024 * 1024;            //  2 MB

    dim3 gc(2048, 5);
    convert_bf16<<<gc, 256, 0, stream>>>(x, Wq, Wk, Wv, Wo, XA, Wb3, Wob);

    dim3 g1(3072 / 128, NROWS / 64);   // 24 x 64 = 1536 blocks
    gemm_qkv<<<g1, 256, 0, stream>>>(XA, Wb3, bq, bk, bv, Qw, Kw, Vw);

    attn<<<512, 512, 0, stream>>>(Qw, Kw, Vw, lam, XA);   // 1D, XCD-swizzled

    dim3 g3(1024 / 64, NROWS / 64);    // 16 x 64 = 1024 blocks
    gemm_out<<<g3, 256, 0, stream>>>(XA, Wob, bo, out);
}